// Round 2
// baseline (2312.938 us; speedup 1.0000x reference)
//
#include <hip/hip_runtime.h>

#define N 8192
#define NITER 20
#define TOLF 1e-10f
#define NBLK 256

typedef float floatx4 __attribute__((ext_vector_type(4)));
typedef unsigned int uintx4 __attribute__((ext_vector_type(4)));

__device__ __forceinline__ unsigned short f2bf_rne(float f) {
  unsigned int u = __float_as_uint(f);
  unsigned int r = u + 0x7fffu + ((u >> 16) & 1u);
  return (unsigned short)(r >> 16);
}
__device__ __forceinline__ unsigned int pk_bf2(float lo, float hi) {
  return (unsigned int)f2bf_rne(lo) | ((unsigned int)f2bf_rne(hi) << 16);
}
__device__ __forceinline__ float bflo(unsigned int u) { return __uint_as_float(u << 16); }
__device__ __forceinline__ float bfhi(unsigned int u) { return __uint_as_float(u & 0xffff0000u); }

// ---- grid barrier (all NBLK blocks co-resident via cooperative launch) ----
// Arrive: acq_rel fetch_add on cnt releases this block's prior plain stores.
// Last arrival acquires all of them, resets cnt, releases via gen bump.
// Spinners acquire gen -> transitively see every block's writes.
// gen cannot advance between a block's g-load and its cnt increment (the
// barrier needs this block's increment to complete), so no missed wakeup.
__device__ __forceinline__ void grid_sync(int* cnt, int* gen) {
  __syncthreads();
  if (threadIdx.x == 0) {
    int g = __hip_atomic_load(gen, __ATOMIC_RELAXED, __HIP_MEMORY_SCOPE_AGENT);
    int t = __hip_atomic_fetch_add(cnt, 1, __ATOMIC_ACQ_REL, __HIP_MEMORY_SCOPE_AGENT);
    if (t == NBLK - 1) {
      __hip_atomic_store(cnt, 0, __ATOMIC_RELAXED, __HIP_MEMORY_SCOPE_AGENT);
      __hip_atomic_fetch_add(gen, 1, __ATOMIC_ACQ_REL, __HIP_MEMORY_SCOPE_AGENT);
    } else {
      while (__hip_atomic_load(gen, __ATOMIC_ACQUIRE, __HIP_MEMORY_SCOPE_AGENT) == g)
        __builtin_amdgcn_s_sleep(1);
    }
  }
  __syncthreads();
}

// ---- sum part[0..NBLK) , broadcast to all threads ----
// Fixed order -> bitwise-identical result in every block (keeps the
// convergence-freeze branch grid-uniform).
__device__ __forceinline__ float sum_part(const float* __restrict__ part, float* lred) {
  float v = (threadIdx.x < NBLK) ? part[threadIdx.x] : 0.0f;
  for (int off = 32; off > 0; off >>= 1) v += __shfl_down(v, off, 64);
  int wave = threadIdx.x >> 6, lane = threadIdx.x & 63;
  if (lane == 0) lred[wave] = v;
  __syncthreads();
  float S = lred[0] + lred[1] + lred[2] + lred[3];
  __syncthreads();  // protect lred reuse by later calls
  return S;
}

__global__ __launch_bounds__(1024, 4) void cg_persistent(
    const float* __restrict__ M, unsigned short* __restrict__ Mb,
    const float* __restrict__ RHS, float* __restrict__ x,
    float* __restrict__ Ap, float* __restrict__ r, float* __restrict__ p,
    float* __restrict__ partA, float* __restrict__ partB,
    int* __restrict__ cnt, int* __restrict__ gen) {
  int b = blockIdx.x;
  int t = threadIdx.x;
  int wave = t >> 6, lane = t & 63;
  __shared__ float lred[16];
  __shared__ float bs[16];

  // ---- init: x=0, r=p=RHS, partB[b] = partial sum(RHS^2) ----
  {
    float val = 0.0f;
    if (t < 32) {
      int i = b * 32 + t;
      float v = RHS[i];
      x[i] = 0.0f;
      r[i] = v;
      p[i] = v;
      val = v * v;
    }
    for (int off = 32; off > 0; off >>= 1) val += __shfl_down(val, off, 64);
    if (t == 0) partB[b] = val;
  }
  grid_sync(cnt, gen);
  float rt = sum_part(partB, lred);

  int row0 = b * 32 + wave * 2;

  for (int k = 0; k < NITER; ++k) {
    bool act = rt > TOLF;  // identical in every thread of every block

    // ---- phase A: matvec (k==0: fp32 M, fused bf16 cast) + pAp partial ----
    if (act) {
      float acc0 = 0.0f, acc1 = 0.0f;
      if (k == 0) {
        const float* M0 = M + (size_t)row0 * N;
        const float* M1 = M0 + N;
        unsigned short* B0 = Mb + (size_t)row0 * N;
        unsigned short* B1 = B0 + N;
#pragma unroll 2
        for (int c = lane * 8; c < N; c += 512) {
          floatx4 a0 = *(const floatx4*)(M0 + c);
          floatx4 a1 = *(const floatx4*)(M0 + c + 4);
          floatx4 b0 = *(const floatx4*)(M1 + c);
          floatx4 b1 = *(const floatx4*)(M1 + c + 4);
          floatx4 pa = *(const floatx4*)(p + c);
          floatx4 pb = *(const floatx4*)(p + c + 4);
          acc0 += a0.x * pa.x + a0.y * pa.y + a0.z * pa.z + a0.w * pa.w
                + a1.x * pb.x + a1.y * pb.y + a1.z * pb.z + a1.w * pb.w;
          acc1 += b0.x * pa.x + b0.y * pa.y + b0.z * pa.z + b0.w * pa.w
                + b1.x * pb.x + b1.y * pb.y + b1.z * pb.z + b1.w * pb.w;
          uintx4 o0 = {pk_bf2(a0.x, a0.y), pk_bf2(a0.z, a0.w),
                       pk_bf2(a1.x, a1.y), pk_bf2(a1.z, a1.w)};
          uintx4 o1 = {pk_bf2(b0.x, b0.y), pk_bf2(b0.z, b0.w),
                       pk_bf2(b1.x, b1.y), pk_bf2(b1.z, b1.w)};
          *(uintx4*)(B0 + c) = o0;
          *(uintx4*)(B1 + c) = o1;
        }
      } else {
        const unsigned short* M0 = Mb + (size_t)row0 * N;
        const unsigned short* M1 = M0 + N;
#pragma unroll 4
        for (int c = lane * 8; c < N; c += 512) {
          uintx4 m0 = *(const uintx4*)(M0 + c);
          uintx4 m1 = *(const uintx4*)(M1 + c);
          floatx4 pa = *(const floatx4*)(p + c);
          floatx4 pb = *(const floatx4*)(p + c + 4);
          acc0 += bflo(m0.x) * pa.x + bfhi(m0.x) * pa.y
                + bflo(m0.y) * pa.z + bfhi(m0.y) * pa.w
                + bflo(m0.z) * pb.x + bfhi(m0.z) * pb.y
                + bflo(m0.w) * pb.z + bfhi(m0.w) * pb.w;
          acc1 += bflo(m1.x) * pa.x + bfhi(m1.x) * pa.y
                + bflo(m1.y) * pa.z + bfhi(m1.y) * pa.w
                + bflo(m1.z) * pb.x + bfhi(m1.z) * pb.y
                + bflo(m1.w) * pb.z + bfhi(m1.w) * pb.w;
        }
      }
      for (int off = 32; off > 0; off >>= 1) {
        acc0 += __shfl_down(acc0, off, 64);
        acc1 += __shfl_down(acc1, off, 64);
      }
      if (lane == 0) {
        Ap[row0] = acc0;
        Ap[row0 + 1] = acc1;
        bs[wave] = p[row0] * acc0 + p[row0 + 1] * acc1;
      }
      __syncthreads();
      if (t == 0) {
        float S = 0.0f;
#pragma unroll
        for (int w = 0; w < 16; ++w) S += bs[w];
        partA[b] = S;
      }
    }
    grid_sync(cnt, gen);

    // ---- phase B: alpha, x/r update on own 32-row slice, rn partial ----
    if (act) {
      float pap = sum_part(partA, lred);
      float alpha = rt / pap;
      float val = 0.0f;
      if (t < 32) {
        int i = b * 32 + t;
        float rv = r[i] - alpha * Ap[i];
        x[i] += alpha * p[i];
        r[i] = rv;
        val = rv * rv;
      }
      for (int off = 32; off > 0; off >>= 1) val += __shfl_down(val, off, 64);
      if (t == 0) partB[b] = val;
    }
    grid_sync(cnt, gen);

    // ---- phase C: beta, p update on own slice ----
    if (act) {
      float rnv = sum_part(partB, lred);
      float beta = rnv / rt;
      if (t < 32) {
        int i = b * 32 + t;
        p[i] = r[i] + beta * p[i];
      }
      rt = rnv;
    }
    grid_sync(cnt, gen);
  }
}

extern "C" void kernel_launch(void* const* d_in, const int* in_sizes, int n_in,
                              void* d_out, int out_size, void* d_ws, size_t ws_size,
                              hipStream_t stream) {
  const float* M   = (const float*)d_in[1];
  const float* RHS = (const float*)d_in[2];
  float* x = (float*)d_out;  // x accumulates directly in d_out

  char* ws = (char*)d_ws;
  unsigned short* Mb = (unsigned short*)ws;              // N*N bf16 = 134 MB
  float* Ap = (float*)(ws + (size_t)N * N * 2);          // N
  float* r  = Ap + N;                                    // N
  float* p  = r + N;                                     // N
  float* partA = p + N;                                  // NBLK
  float* partB = partA + NBLK;                           // NBLK
  int* cnt = (int*)(partB + NBLK);
  int* gen = cnt + 1;

  // Only the barrier state must be zeroed; all partials are written before read.
  (void)hipMemsetAsync(cnt, 0, 2 * sizeof(int), stream);

  void* args[] = {(void*)&M, (void*)&Mb, (void*)&RHS, (void*)&x, (void*)&Ap,
                  (void*)&r, (void*)&p, (void*)&partA, (void*)&partB,
                  (void*)&cnt, (void*)&gen};
  (void)hipLaunchCooperativeKernel((void*)cg_persistent, dim3(NBLK), dim3(1024),
                                   args, 0, stream);
}

// Round 6
// 876.699 us; speedup vs baseline: 2.6382x; 2.6382x over previous
//
#include <hip/hip_runtime.h>

#define N 8192
#define NITER 20
#define TOLF 1e-10f

typedef float floatx4 __attribute__((ext_vector_type(4)));
typedef unsigned int uintx4 __attribute__((ext_vector_type(4)));

__device__ __forceinline__ unsigned short f2bf_rne(float f) {
  unsigned int u = __float_as_uint(f);
  unsigned int r = u + 0x7fffu + ((u >> 16) & 1u);
  return (unsigned short)(r >> 16);
}
__device__ __forceinline__ unsigned int pk_bf2(float lo, float hi) {
  return (unsigned int)f2bf_rne(lo) | ((unsigned int)f2bf_rne(hi) << 16);
}
__device__ __forceinline__ float bflo(unsigned int u) { return __uint_as_float(u << 16); }
__device__ __forceinline__ float bfhi(unsigned int u) { return __uint_as_float(u & 0xffff0000u); }

// p staged in LDS, deinterleaved: pA holds cols with c%8<4, pB holds c%8>=4,
// packed floatx4 per 8-col chunk. Lane reads pA[s*64+lane]: 16B lane stride,
// conflict-free ds_read_b128.
__device__ __forceinline__ float lds_pget(const float* pAf, const float* pBf, int c) {
  int idx = ((c >> 3) << 2) | (c & 3);
  return (c & 4) ? pBf[idx] : pAf[idx];
}

// ---------------- init: x=0, r=RHS, rt0 = sum(RHS^2) ----------------
__global__ __launch_bounds__(256) void init_kernel(
    const float* __restrict__ RHS, float* __restrict__ x, float* __restrict__ r,
    float* __restrict__ rt0) {
  int i = blockIdx.x * 256 + threadIdx.x;
  float v = RHS[i];
  x[i] = 0.0f;
  r[i] = v;
  float val = v * v;
  for (int off = 32; off > 0; off >>= 1) val += __shfl_down(val, off, 64);
  __shared__ float bs[4];
  int wave = threadIdx.x >> 6, lane = threadIdx.x & 63;
  if (lane == 0) bs[wave] = val;
  __syncthreads();
  if (threadIdx.x == 0) atomicAdd(rt0, bs[0] + bs[1] + bs[2] + bs[3]);
}

// ---- matvec tail: reduce row-pair accs, publish Ap, atomicAdd pAp ----
__device__ __forceinline__ void matvec_tail(
    float acc0, float acc1, int row0,
    const float* pAf, const float* pBf,
    float* __restrict__ Ap, float* pap, float* bsP) {
  int wave = threadIdx.x >> 6, lane = threadIdx.x & 63;
  for (int off = 32; off > 0; off >>= 1) {
    acc0 += __shfl_down(acc0, off, 64);
    acc1 += __shfl_down(acc1, off, 64);
  }
  if (lane == 0) {
    Ap[row0]     = acc0;
    Ap[row0 + 1] = acc1;
    bsP[wave] = lds_pget(pAf, pBf, row0) * acc0
              + lds_pget(pAf, pBf, row0 + 1) * acc1;
  }
  __syncthreads();
  if (threadIdx.x == 0) {
    float SP = 0.f;
#pragma unroll
    for (int w = 0; w < 16; ++w) SP += bsP[w];
    atomicAdd(pap, SP);
  }
}

// ------- matvec 0: p0 = RHS; fp32 M matvec fused with bf16 cast -------
__global__ __launch_bounds__(1024, 4) void matvec0_cast(
    const float* __restrict__ M, unsigned short* __restrict__ Mb,
    const float* __restrict__ RHS, float* __restrict__ p0,
    float* __restrict__ Ap, float* __restrict__ pap) {
  __shared__ floatx4 pA[1024], pB[1024];
  __shared__ float bsP[16];
  int b = blockIdx.x, t = threadIdx.x;
  int c = t * 8;
  floatx4 va = *(const floatx4*)(RHS + c);
  floatx4 vb = *(const floatx4*)(RHS + c + 4);
  pA[t] = va;
  pB[t] = vb;
  if ((t >> 2) == b) {  // own 32-elem slice: materialize p0 for update_ew
    *(floatx4*)(p0 + c) = va;
    *(floatx4*)(p0 + c + 4) = vb;
  }
  __syncthreads();

  int wave = t >> 6, lane = t & 63;
  int row0 = b * 32 + wave * 2;
  const float* M0 = M + (size_t)row0 * N;
  const float* M1 = M0 + N;
  unsigned short* B0 = Mb + (size_t)row0 * N;
  unsigned short* B1 = B0 + N;
  float acc0 = 0.f, acc1 = 0.f;
#pragma unroll 2
  for (int s = 0; s < 16; ++s) {
    int cc = s * 512 + lane * 8;
    floatx4 a0 = *(const floatx4*)(M0 + cc);
    floatx4 a1 = *(const floatx4*)(M0 + cc + 4);
    floatx4 b0 = *(const floatx4*)(M1 + cc);
    floatx4 b1 = *(const floatx4*)(M1 + cc + 4);
    floatx4 pa = pA[s * 64 + lane];
    floatx4 pb = pB[s * 64 + lane];
    acc0 += a0.x*pa.x + a0.y*pa.y + a0.z*pa.z + a0.w*pa.w
          + a1.x*pb.x + a1.y*pb.y + a1.z*pb.z + a1.w*pb.w;
    acc1 += b0.x*pa.x + b0.y*pa.y + b0.z*pa.z + b0.w*pa.w
          + b1.x*pb.x + b1.y*pb.y + b1.z*pb.z + b1.w*pb.w;
    uintx4 o0 = {pk_bf2(a0.x, a0.y), pk_bf2(a0.z, a0.w),
                 pk_bf2(a1.x, a1.y), pk_bf2(a1.z, a1.w)};
    uintx4 o1 = {pk_bf2(b0.x, b0.y), pk_bf2(b0.z, b0.w),
                 pk_bf2(b1.x, b1.y), pk_bf2(b1.z, b1.w)};
    *(uintx4*)(B0 + cc) = o0;
    *(uintx4*)(B1 + cc) = o1;
  }
  matvec_tail(acc0, acc1, row0, (const float*)pA, (const float*)pB, Ap, pap, bsP);
}

// ------- matvec k>=1: p_k = r + beta*p_old formed at head, then bf16 matvec ---
// beta = RT[k]/RT[k-1], both written by prior launches (stream-ordered).
// Gate (RT[k] > TOL) is a single global scalar -> uniform across the grid.
__global__ __launch_bounds__(1024, 4) void matvec_step(
    const unsigned short* __restrict__ Mb, const float* __restrict__ r,
    const float* __restrict__ p_old, float* __restrict__ p_new,
    float* __restrict__ Ap, const float* __restrict__ rt_prev,
    const float* __restrict__ rt_cur, float* __restrict__ pap) {
  __shared__ floatx4 pA[1024], pB[1024];
  __shared__ float bsP[16];
  int b = blockIdx.x, t = threadIdx.x;
  int c = t * 8;

  float rtc = *rt_cur;                 // RT[k] = ||r_k||^2 (explicit sum)
  if (!(rtc > TOLF)) {                 // frozen: state unchanged; keep buffers consistent
    if ((t >> 2) == b) {
      *(floatx4*)(p_new + c)     = *(const floatx4*)(p_old + c);
      *(floatx4*)(p_new + c + 4) = *(const floatx4*)(p_old + c + 4);
    }
    return;
  }
  float beta = rtc / *rt_prev;

  floatx4 rv0 = *(const floatx4*)(r + c);
  floatx4 rv1 = *(const floatx4*)(r + c + 4);
  floatx4 po0 = *(const floatx4*)(p_old + c);
  floatx4 po1 = *(const floatx4*)(p_old + c + 4);
  floatx4 pv0 = rv0 + beta * po0;
  floatx4 pv1 = rv1 + beta * po1;
  pA[t] = pv0;
  pB[t] = pv1;
  if ((t >> 2) == b) {  // own slice: materialize p_k for update_ew / next iter
    *(floatx4*)(p_new + c)     = pv0;
    *(floatx4*)(p_new + c + 4) = pv1;
  }
  __syncthreads();

  int wave = t >> 6, lane = t & 63;
  int row0 = b * 32 + wave * 2;
  const unsigned short* M0 = Mb + (size_t)row0 * N;
  const unsigned short* M1 = M0 + N;
  float acc0 = 0.f, acc1 = 0.f;
#pragma unroll 4
  for (int s = 0; s < 16; ++s) {
    int cc = s * 512 + lane * 8;
    uintx4 m0 = *(const uintx4*)(M0 + cc);
    uintx4 m1 = *(const uintx4*)(M1 + cc);
    floatx4 pa = pA[s * 64 + lane];
    floatx4 pb = pB[s * 64 + lane];
    acc0 += bflo(m0.x) * pa.x + bfhi(m0.x) * pa.y
          + bflo(m0.y) * pa.z + bfhi(m0.y) * pa.w
          + bflo(m0.z) * pb.x + bfhi(m0.z) * pb.y
          + bflo(m0.w) * pb.z + bfhi(m0.w) * pb.w;
    acc1 += bflo(m1.x) * pa.x + bfhi(m1.x) * pa.y
          + bflo(m1.y) * pa.z + bfhi(m1.y) * pa.w
          + bflo(m1.z) * pb.x + bfhi(m1.z) * pb.y
          + bflo(m1.w) * pb.z + bfhi(m1.w) * pb.w;
  }
  matvec_tail(acc0, acc1, row0, (const float*)pA, (const float*)pB, Ap, pap, bsP);
}

// ------- update: x += a*p; r -= a*Ap; EXPLICIT rn = sum(r_new^2) -> RT[k+1] ---
__global__ __launch_bounds__(256) void update_ew(
    const float* __restrict__ Ap, const float* __restrict__ p,
    float* __restrict__ x, float* __restrict__ r,
    const float* __restrict__ rt, const float* __restrict__ pap,
    float* __restrict__ rt_next) {
  float rtv = *rt;
  bool act = rtv > TOLF;
  if (!act) {
    if (blockIdx.x == 0 && threadIdx.x == 0) *rt_next = rtv;  // freeze rt
    return;
  }
  float a = rtv / *pap;
  int base = (blockIdx.x * 256 + threadIdx.x) * 4;
  floatx4 pv = *(const floatx4*)(p + base);
  floatx4 av = *(const floatx4*)(Ap + base);
  floatx4 xv = *(const floatx4*)(x + base);
  floatx4 rv = *(const floatx4*)(r + base);
  xv += a * pv;
  rv -= a * av;
  *(floatx4*)(x + base) = xv;
  *(floatx4*)(r + base) = rv;
  float val = rv.x * rv.x + rv.y * rv.y + rv.z * rv.z + rv.w * rv.w;
  for (int off = 32; off > 0; off >>= 1) val += __shfl_down(val, off, 64);
  __shared__ float bs[4];
  int wave = threadIdx.x >> 6, lane = threadIdx.x & 63;
  if (lane == 0) bs[wave] = val;
  __syncthreads();
  if (threadIdx.x == 0) atomicAdd(rt_next, bs[0] + bs[1] + bs[2] + bs[3]);
}

extern "C" void kernel_launch(void* const* d_in, const int* in_sizes, int n_in,
                              void* d_out, int out_size, void* d_ws, size_t ws_size,
                              hipStream_t stream) {
  const float* M   = (const float*)d_in[1];
  const float* RHS = (const float*)d_in[2];
  float* x = (float*)d_out;  // x accumulates directly in d_out

  char* ws = (char*)d_ws;
  unsigned short* Mb = (unsigned short*)ws;              // N*N bf16 = 134 MB
  float* Ap = (float*)(ws + (size_t)N * N * 2);          // N
  float* r  = Ap + N;                                    // N
  float* P0 = r + N;                                     // N
  float* P1 = P0 + N;                                    // N
  float* sc = P1 + N;
  float* RT  = sc;           // [0..NITER]  21
  float* PAP = sc + 21;      // 20 -> 41 floats total

  (void)hipMemsetAsync(sc, 0, 41 * sizeof(float), stream);

  float* P[2] = {P0, P1};

  init_kernel<<<N / 256, 256, 0, stream>>>(RHS, x, r, &RT[0]);
  matvec0_cast<<<N / 32, 1024, 0, stream>>>(M, Mb, RHS, P[0], Ap, &PAP[0]);
  update_ew<<<N / 1024, 256, 0, stream>>>(Ap, P[0], x, r, &RT[0], &PAP[0], &RT[1]);
  for (int k = 1; k < NITER; ++k) {
    matvec_step<<<N / 32, 1024, 0, stream>>>(Mb, r, P[(k - 1) & 1], P[k & 1],
                                             Ap, &RT[k - 1], &RT[k], &PAP[k]);
    update_ew<<<N / 1024, 256, 0, stream>>>(Ap, P[k & 1], x, r, &RT[k],
                                            &PAP[k], &RT[k + 1]);
  }
}

// Round 7
// 864.531 us; speedup vs baseline: 2.6754x; 1.0141x over previous
//
#include <hip/hip_runtime.h>

#define N 8192
#define NITER 20
#define TOLF 1e-10f

typedef float floatx4 __attribute__((ext_vector_type(4)));
typedef unsigned int uintx4 __attribute__((ext_vector_type(4)));

__device__ __forceinline__ unsigned short f2bf_rne(float f) {
  unsigned int u = __float_as_uint(f);
  unsigned int r = u + 0x7fffu + ((u >> 16) & 1u);
  return (unsigned short)(r >> 16);
}
__device__ __forceinline__ unsigned int pk_bf2(float lo, float hi) {
  return (unsigned int)f2bf_rne(lo) | ((unsigned int)f2bf_rne(hi) << 16);
}
__device__ __forceinline__ float bflo(unsigned int u) { return __uint_as_float(u << 16); }
__device__ __forceinline__ float bfhi(unsigned int u) { return __uint_as_float(u & 0xffff0000u); }

// p staged in LDS, deinterleaved: pA holds cols with c%8<4, pB holds c%8>=4,
// packed floatx4 per 8-col chunk. Lane reads pA[s*64+lane]: 16B lane stride,
// conflict-free ds_read_b128.
__device__ __forceinline__ float lds_pget(const float* pAf, const float* pBf, int c) {
  int idx = ((c >> 3) << 2) | (c & 3);
  return (c & 4) ? pBf[idx] : pAf[idx];
}

// Block-wide sum over 1024 threads; same value returned in every thread.
// Fixed reduction order -> bitwise identical across blocks (grid-uniform
// beta / freeze gate without any cross-block communication).
__device__ __forceinline__ float block_sum_1024(float val, float* red) {
  for (int off = 32; off > 0; off >>= 1) val += __shfl_down(val, off, 64);
  int wave = threadIdx.x >> 6, lane = threadIdx.x & 63;
  if (lane == 0) red[wave] = val;
  __syncthreads();
  float S = 0.f;
#pragma unroll
  for (int w = 0; w < 16; ++w) S += red[w];
  return S;
}

// ---- matvec tail: reduce row-pair accs, publish Ap rows, atomicAdd pAp ----
__device__ __forceinline__ void matvec_tail(
    float acc0, float acc1, int row0,
    const float* pAf, const float* pBf,
    float* __restrict__ Ap, float* pap, float* bsP) {
  int wave = threadIdx.x >> 6, lane = threadIdx.x & 63;
  for (int off = 32; off > 0; off >>= 1) {
    acc0 += __shfl_down(acc0, off, 64);
    acc1 += __shfl_down(acc1, off, 64);
  }
  if (lane == 0) {
    Ap[row0]     = acc0;
    Ap[row0 + 1] = acc1;
    bsP[wave] = lds_pget(pAf, pBf, row0) * acc0
              + lds_pget(pAf, pBf, row0 + 1) * acc1;
  }
  __syncthreads();
  if (threadIdx.x == 0) {
    float SP = 0.f;
#pragma unroll
    for (int w = 0; w < 16; ++w) SP += bsP[w];
    atomicAdd(pap, SP);
  }
}

// ------- K_0: x=0, rt0=||RHS||^2, Ap0 = M@RHS (fp32) fused with bf16 cast ----
__global__ __launch_bounds__(1024, 4) void cg_first(
    const float* __restrict__ M, unsigned short* __restrict__ Mb,
    const float* __restrict__ RHS, float* __restrict__ x,
    float* __restrict__ ap0, float* __restrict__ rt0, float* __restrict__ pap0) {
  __shared__ floatx4 pA[1024], pB[1024];
  __shared__ float redA[16], bsP[16];
  int b = blockIdx.x, t = threadIdx.x;
  int c = t * 8;
  floatx4 va = *(const floatx4*)(RHS + c);
  floatx4 vb = *(const floatx4*)(RHS + c + 4);
  pA[t] = va;
  pB[t] = vb;
  if ((t >> 2) == b) {  // own 32-elem slice: x = 0
    floatx4 z = {0.f, 0.f, 0.f, 0.f};
    *(floatx4*)(x + c) = z;
    *(floatx4*)(x + c + 4) = z;
  }
  float val = va.x*va.x + va.y*va.y + va.z*va.z + va.w*va.w
            + vb.x*vb.x + vb.y*vb.y + vb.z*vb.z + vb.w*vb.w;
  float rt = block_sum_1024(val, redA);  // internal sync also covers pA/pB
  if (b == 0 && t == 0) *rt0 = rt;

  int wave = t >> 6, lane = t & 63;
  int row0 = b * 32 + wave * 2;
  const float* M0 = M + (size_t)row0 * N;
  const float* M1 = M0 + N;
  unsigned short* B0 = Mb + (size_t)row0 * N;
  unsigned short* B1 = B0 + N;
  float acc0 = 0.f, acc1 = 0.f;
#pragma unroll 2
  for (int s = 0; s < 16; ++s) {
    int cc = s * 512 + lane * 8;
    floatx4 a0 = *(const floatx4*)(M0 + cc);
    floatx4 a1 = *(const floatx4*)(M0 + cc + 4);
    floatx4 b0 = *(const floatx4*)(M1 + cc);
    floatx4 b1 = *(const floatx4*)(M1 + cc + 4);
    floatx4 pa = pA[s * 64 + lane];
    floatx4 pb = pB[s * 64 + lane];
    acc0 += a0.x*pa.x + a0.y*pa.y + a0.z*pa.z + a0.w*pa.w
          + a1.x*pb.x + a1.y*pb.y + a1.z*pb.z + a1.w*pb.w;
    acc1 += b0.x*pa.x + b0.y*pa.y + b0.z*pa.z + b0.w*pa.w
          + b1.x*pb.x + b1.y*pb.y + b1.z*pb.z + b1.w*pb.w;
    uintx4 o0 = {pk_bf2(a0.x, a0.y), pk_bf2(a0.z, a0.w),
                 pk_bf2(a1.x, a1.y), pk_bf2(a1.z, a1.w)};
    uintx4 o1 = {pk_bf2(b0.x, b0.y), pk_bf2(b0.z, b0.w),
                 pk_bf2(b1.x, b1.y), pk_bf2(b1.z, b1.w)};
    *(uintx4*)(B0 + cc) = o0;
    *(uintx4*)(B1 + cc) = o1;
  }
  matvec_tail(acc0, acc1, row0, (const float*)pA, (const float*)pB, ap0, pap0, bsP);
}

// ------- K_k (k>=1): iter k-1 tail (x,r update; rn) + iter k head (p, matvec) --
// alpha from prev launch's scalars (stream-ordered). rn computed redundantly
// and deterministically in EVERY block (explicit sum of squares, no
// cancellation, no atomics in the beta path). All cross-launch vectors are
// double-buffered; own-slice writes only.
__global__ __launch_bounds__(1024, 4) void cg_fused(
    const unsigned short* __restrict__ Mb,
    const float* __restrict__ r_old, float* __restrict__ r_new,
    const float* __restrict__ p_old, float* __restrict__ p_new,
    const float* __restrict__ ap_old, float* __restrict__ ap_new,
    float* __restrict__ x,
    const float* __restrict__ rt_prev_p, const float* __restrict__ pap_prev_p,
    float* __restrict__ rt_out, float* __restrict__ pap_out) {
  __shared__ floatx4 pA[1024], pB[1024];
  __shared__ float redA[16], bsP[16];
  int b = blockIdx.x, t = threadIdx.x;
  int c = t * 8;

  float rt_prev = *rt_prev_p;
  bool act_prev = rt_prev > TOLF;                   // grid-uniform scalar
  float alpha = act_prev ? rt_prev / *pap_prev_p : 0.0f;

  floatx4 ro0 = *(const floatx4*)(r_old + c);
  floatx4 ro1 = *(const floatx4*)(r_old + c + 4);
  floatx4 po0 = *(const floatx4*)(p_old + c);
  floatx4 po1 = *(const floatx4*)(p_old + c + 4);
  floatx4 ao0 = *(const floatx4*)(ap_old + c);
  floatx4 ao1 = *(const floatx4*)(ap_old + c + 4);

  // r_k (frozen: exact copy of r_old; no arithmetic with possibly-stale Ap)
  floatx4 rv0 = act_prev ? (ro0 - alpha * ao0) : ro0;
  floatx4 rv1 = act_prev ? (ro1 - alpha * ao1) : ro1;

  float val = rv0.x*rv0.x + rv0.y*rv0.y + rv0.z*rv0.z + rv0.w*rv0.w
            + rv1.x*rv1.x + rv1.y*rv1.y + rv1.z*rv1.z + rv1.w*rv1.w;
  float rn = block_sum_1024(val, redA);             // identical in all blocks
  float rn_rep = act_prev ? rn : rt_prev;           // freeze semantics
  bool act = rn_rep > TOLF;
  float beta = act_prev ? rn / rt_prev : 0.0f;

  floatx4 pv0 = act_prev ? (rv0 + beta * po0) : po0;
  floatx4 pv1 = act_prev ? (rv1 + beta * po1) : po1;
  pA[t] = pv0;
  pB[t] = pv1;

  if ((t >> 2) == b) {  // own 32-elem slice: x update + r/p materialization
    if (act_prev) {
      floatx4 xv0 = *(const floatx4*)(x + c);
      floatx4 xv1 = *(const floatx4*)(x + c + 4);
      xv0 += alpha * po0;
      xv1 += alpha * po1;
      *(floatx4*)(x + c) = xv0;
      *(floatx4*)(x + c + 4) = xv1;
    }
    *(floatx4*)(r_new + c)     = rv0;
    *(floatx4*)(r_new + c + 4) = rv1;
    *(floatx4*)(p_new + c)     = pv0;
    *(floatx4*)(p_new + c + 4) = pv1;
  }
  if (b == 0 && t == 0) *rt_out = rn_rep;
  __syncthreads();      // pA/pB staged for all waves

  if (!act) return;     // frozen: matvec skipped (PAP stays 0; never read)

  int wave = t >> 6, lane = t & 63;
  int row0 = b * 32 + wave * 2;
  const unsigned short* M0 = Mb + (size_t)row0 * N;
  const unsigned short* M1 = M0 + N;
  float acc0 = 0.f, acc1 = 0.f;
#pragma unroll 4
  for (int s = 0; s < 16; ++s) {
    int cc = s * 512 + lane * 8;
    uintx4 m0 = *(const uintx4*)(M0 + cc);
    uintx4 m1 = *(const uintx4*)(M1 + cc);
    floatx4 pa = pA[s * 64 + lane];
    floatx4 pb = pB[s * 64 + lane];
    acc0 += bflo(m0.x) * pa.x + bfhi(m0.x) * pa.y
          + bflo(m0.y) * pa.z + bfhi(m0.y) * pa.w
          + bflo(m0.z) * pb.x + bfhi(m0.z) * pb.y
          + bflo(m0.w) * pb.z + bfhi(m0.w) * pb.w;
    acc1 += bflo(m1.x) * pa.x + bfhi(m1.x) * pa.y
          + bflo(m1.y) * pa.z + bfhi(m1.y) * pa.w
          + bflo(m1.z) * pb.x + bfhi(m1.z) * pb.y
          + bflo(m1.w) * pb.z + bfhi(m1.w) * pb.w;
  }
  matvec_tail(acc0, acc1, row0, (const float*)pA, (const float*)pB,
              ap_new, pap_out, bsP);
}

// ------- final: apply iteration NITER-1's x update only ----
__global__ __launch_bounds__(256) void cg_final(
    float* __restrict__ x, const float* __restrict__ p_last,
    const float* __restrict__ rt_ptr, const float* __restrict__ pap_ptr) {
  float rt = *rt_ptr;
  if (!(rt > TOLF)) return;
  float a = rt / *pap_ptr;
  int base = (blockIdx.x * 256 + threadIdx.x) * 4;
  floatx4 xv = *(const floatx4*)(x + base);
  floatx4 pv = *(const floatx4*)(p_last + base);
  xv += a * pv;
  *(floatx4*)(x + base) = xv;
}

extern "C" void kernel_launch(void* const* d_in, const int* in_sizes, int n_in,
                              void* d_out, int out_size, void* d_ws, size_t ws_size,
                              hipStream_t stream) {
  const float* M   = (const float*)d_in[1];
  const float* RHS = (const float*)d_in[2];
  float* x = (float*)d_out;  // x accumulates directly in d_out

  char* ws = (char*)d_ws;
  unsigned short* Mb = (unsigned short*)ws;              // N*N bf16 = 134 MB
  float* A0 = (float*)(ws + (size_t)N * N * 2);          // Ap double buffer
  float* A1 = A0 + N;
  float* R0 = A1 + N;                                    // r double buffer
  float* R1 = R0 + N;
  float* P0 = R1 + N;                                    // p double buffer
  float* P1 = P0 + N;
  float* sc = P1 + N;
  float* RT  = sc;           // RT[0..NITER-1]  (20)
  float* PAP = sc + 20;      // PAP[0..NITER-1] (20) -> 40 floats

  (void)hipMemsetAsync(sc, 0, 40 * sizeof(float), stream);

  float* Ab[2] = {A0, A1};
  float* Rb[2] = {R0, R1};
  float* Pb[2] = {P0, P1};

  cg_first<<<N / 32, 1024, 0, stream>>>(M, Mb, RHS, x, Ab[0], &RT[0], &PAP[0]);
  for (int k = 1; k < NITER; ++k) {
    const float* rold = (k == 1) ? RHS : Rb[(k - 1) & 1];
    const float* pold = (k == 1) ? RHS : Pb[(k - 1) & 1];
    cg_fused<<<N / 32, 1024, 0, stream>>>(Mb, rold, Rb[k & 1], pold, Pb[k & 1],
                                          Ab[(k - 1) & 1], Ab[k & 1], x,
                                          &RT[k - 1], &PAP[k - 1],
                                          &RT[k], &PAP[k]);
  }
  cg_final<<<N / 1024, 256, 0, stream>>>(x, Pb[(NITER - 1) & 1],
                                         &RT[NITER - 1], &PAP[NITER - 1]);
}